// Round 9
// baseline (44.892 us; speedup 1.0000x reference)
//
#include <hip/hip_runtime.h>
#include <math.h>

#define IMG 128
#define NPIX (IMG * IMG)
#define NF 1024
#define NCHUNK 16
#define CHF 64                     // faces per chunk
#define NEAR_Z 0.1f
#define DY 0.015625f               // 2/IMG, exact power-of-2 step

struct AllViews { float m[4][12]; };  // per view: xax[3], yax[3], zax[3], eye[3]

__device__ __forceinline__ float fast_tanh(float x)
{
    float xc = fminf(fmaxf(x, -10.0f), 10.0f);
    float e = __expf(2.0f * xc);
    return __fdividef(e - 1.0f, e + 1.0f);
}

// Record (3 x float4):
//   Q0 = (a1x, a1y, b1, ddx)   w1  = a1.p + b1
//   Q1 = (a2x, a2y, b2, ddy)   w2  = a2.p + b2
//   Q2 = (dc, 0, 0, 0)         dep = ddx*sx + ddy*sy + dc
// !ok -> all-zero planes -> dep = 0 < NEAR -> invisible (matches ref `ok`).
__global__ void precompute(const float* __restrict__ verts,
                           const int* __restrict__ faces,
                           float4* __restrict__ fd,
                           unsigned int* __restrict__ counter,
                           AllViews vc, float W)
{
    int t = blockIdx.x * blockDim.x + threadIdx.x;
    if (t == 0) *counter = 0;         // reset for shade's last-block pattern
    if (t >= 4 * NF) return;
    int view = t >> 10, f = t & (NF - 1);
    const float* M = vc.m[view];

    float proj[3][3];
#pragma unroll
    for (int k = 0; k < 3; ++k) {
        int vi = faces[f * 3 + k];
        float px = verts[vi * 3 + 0] - M[9];
        float py = verts[vi * 3 + 1] - M[10];
        float pz = verts[vi * 3 + 2] - M[11];
        float x = M[0] * px + M[1] * py + M[2] * pz;
        float y = M[3] * px + M[4] * py + M[5] * pz;
        float z = M[6] * px + M[7] * py + M[8] * pz;
        proj[k][0] = x / (z * W);
        proj[k][1] = y / (z * W);
        proj[k][2] = z;
    }
    float v0x = proj[0][0], v0y = proj[0][1];
    float e1x = proj[1][0] - v0x, e1y = proj[1][1] - v0y;
    float e2x = proj[2][0] - v0x, e2y = proj[2][1] - v0y;
    float det = e1x * e2y - e1y * e2x;
    bool ok = fabsf(det) > 1e-8f;
    float inv = ok ? 1.0f / det : 0.0f;
    float a1x = e2y * inv, a1y = -e2x * inv;
    float b1 = -(a1x * v0x + a1y * v0y);
    float a2x = -e1y * inv, a2y = e1x * inv;
    float b2 = -(a2x * v0x + a2y * v0y);
    float z0 = ok ? proj[0][2] : 0.0f;
    float g1 = proj[1][2] - proj[0][2];
    float g2 = proj[2][2] - proj[0][2];
    float ddx = ok ? (g1 * a1x + g2 * a2x) : 0.0f;
    float ddy = ok ? (g1 * a1y + g2 * a2y) : 0.0f;
    float dc  = ok ? (z0 + g1 * b1 + g2 * b2) : 0.0f;

    float4* o = fd + (size_t)t * 3;
    o[0] = make_float4(a1x, a1y, b1, ddx);
    o[1] = make_float4(a2x, a2y, b2, ddy);
    o[2] = make_float4(dc, 0.0f, 0.0f, 0.0f);
}

// Block = (view, 8-row tile, 64-face chunk): 1024 blocks, 4/CU.
// Dense straight-line scan: NO cull, NO branches. 4 px/thread
// (2 rows x cols lane,lane+64; exact fp32 increments). No atomics.
__global__ __launch_bounds__(256, 4) void raster(
    const float4* __restrict__ fd,
    unsigned long long* __restrict__ keys)
{
    __shared__ float4 lds4[CHF * 3];   // 3 KB

    int bid = blockIdx.x;
    int view  = bid >> 8;          // 256 blocks per view
    int b     = bid & 255;
    int chunk = b & (NCHUNK - 1);
    int tile  = b >> 4;            // 0..15, 8 rows each
    int tid  = threadIdx.x;
    int wave = tid >> 6, lane = tid & 63;

    const float4* src = fd + (size_t)(view * NF + chunk * CHF) * 3;
    if (tid < CHF * 3) lds4[tid] = src[tid];
    __syncthreads();

    int r0 = tile * 8 + wave * 2;              // this wave: rows r0, r0+1
    float sy0 = 1.0f - (r0 + 0.5f) * DY;
    float sx0 = (lane + 0.5f) * DY - 1.0f;     // cols lane and lane+64 (+1.0)

    float bst[4] = {INFINITY, INFINITY, INFINITY, INFINITY};
    int   bfi[4] = {0, 0, 0, 0};
    const float* ldsf = (const float*)lds4;

#pragma unroll 4
    for (int f = 0; f < CHF; ++f) {
        float4 q0 = lds4[f * 3 + 0];   // a1x a1y b1 ddx
        float4 q1 = lds4[f * 3 + 1];   // a2x a2y b2 ddy
        float dc  = ldsf[f * 12 + 8];
        float w1_00 = fmaf(q0.x, sx0, fmaf(q0.y, sy0, q0.z));
        float w2_00 = fmaf(q1.x, sx0, fmaf(q1.y, sy0, q1.z));
        float dp_00 = fmaf(q0.w, sx0, fmaf(q1.w, sy0, dc));
        float w1_01 = w1_00 + q0.x;            // col+64 (sx+1.0 exact)
        float w2_01 = w2_00 + q1.x;
        float dp_01 = dp_00 + q0.w;
        float w1_10 = fmaf(q0.y, -DY, w1_00);  // row+1
        float w2_10 = fmaf(q1.y, -DY, w2_00);
        float dp_10 = fmaf(q1.w, -DY, dp_00);
        float w1_11 = w1_10 + q0.x;
        float w2_11 = w2_10 + q1.x;
        float dp_11 = dp_10 + q0.w;
        float w1q[4] = {w1_00, w1_01, w1_10, w1_11};
        float w2q[4] = {w2_00, w2_01, w2_10, w2_11};
        float dpq[4] = {dp_00, dp_01, dp_10, dp_11};
#pragma unroll
        for (int q = 0; q < 4; ++q) {
            float w1 = w1q[q], w2 = w2q[q], dep = dpq[q];
            bool vis = (fminf(w1, w2) >= 0.0f) && (w1 + w2 <= 1.0f) &&
                       (dep > NEAR_Z);
            bool take = vis && (dep < bst[q]);   // strict <: lowest f wins
            bst[q] = take ? dep : bst[q];
            bfi[q] = take ? f : bfi[q];
        }
    }

    size_t base = ((size_t)(view * NCHUNK + chunk) << 14);
    int fo = chunk * CHF;
#pragma unroll
    for (int q = 0; q < 4; ++q) {
        unsigned long long key =
            ((unsigned long long)__float_as_uint(bst[q]) << 32) |
            (unsigned int)(fo + bfi[q]);
        keys[base + (r0 + (q >> 1)) * IMG + lane + (q & 1) * 64] = key;
    }
}

// One thread per (view,pixel): min over 16 chunk keys, winner planes from fd,
// trilinear tanh texture, loss; last block does fixed-order final reduce.
__global__ __launch_bounds__(256) void shade_loss(
    const float4* __restrict__ fd,
    const unsigned long long* __restrict__ keys,
    const float* __restrict__ tex,
    const float* __restrict__ refs,
    float* __restrict__ partial, unsigned int* __restrict__ counter,
    float* __restrict__ out)
{
    __shared__ float wsum[4];
    __shared__ bool last;
    int tid = threadIdx.x;
    int t = blockIdx.x * 256 + tid;
    int view = t >> 14, p = t & (NPIX - 1);
    int row = p >> 7, col = p & 127;
    float sx = (col + 0.5f) * DY - 1.0f;
    float sy = 1.0f - (row + 0.5f) * DY;

    const unsigned long long* kb = keys + ((size_t)(view * NCHUNK) << 14) + p;
    unsigned long long key = ~0ULL;
#pragma unroll
    for (int c = 0; c < NCHUNK; ++c) {
        unsigned long long k = kb[(size_t)c << 14];
        key = (k < key) ? k : key;
    }

    bool hit = (unsigned int)(key >> 32) < 0x7f800000u;
    float ref = refs[t];
    float lossv;
    if (hit) {
        int f = (int)(key & 0xffffffffu);
        const float4* Q = fd + (size_t)(view * NF + f) * 3;
        float4 q0 = Q[0];
        float4 q1 = Q[1];
        float w1 = fmaf(q0.x, sx, fmaf(q0.y, sy, q0.z));
        float w2 = fmaf(q1.x, sx, fmaf(q1.y, sy, q1.z));
        float w0 = 1.0f - w1 - w2;
        float cx = fminf(fmaxf(w0, 0.0f), 1.0f) * 3.0f;
        float cy = fminf(fmaxf(w1, 0.0f), 1.0f) * 3.0f;
        float cz = fminf(fmaxf(w2, 0.0f), 1.0f) * 3.0f;
        int ix = min(max((int)floorf(cx), 0), 2);
        int iy = min(max((int)floorf(cy), 0), 2);
        int iz = min(max((int)floorf(cz), 0), 2);
        float fx = cx - (float)ix, fy = cy - (float)iy, fz = cz - (float)iz;

        const float* T = tex + (size_t)f * 192;   // 4*4*4*3
        float c0 = 0.0f, c1 = 0.0f, c2 = 0.0f;
#pragma unroll
        for (int dxi = 0; dxi < 2; ++dxi)
#pragma unroll
            for (int dyi = 0; dyi < 2; ++dyi)
#pragma unroll
                for (int dzi = 0; dzi < 2; ++dzi) {
                    float w = (dxi ? fx : 1.0f - fx) *
                              (dyi ? fy : 1.0f - fy) *
                              (dzi ? fz : 1.0f - fz);
                    int base = (((ix + dxi) * 4 + (iy + dyi)) * 4 + (iz + dzi)) * 3;
                    c0 += w * fast_tanh(T[base + 0]);
                    c1 += w * fast_tanh(T[base + 1]);
                    c2 += w * fast_tanh(T[base + 2]);
                }
        float d0 = c0 - ref, d1 = c1 - ref, d2 = c2 - ref;
        lossv = d0 * d0 + d1 * d1 + d2 * d2;
    } else {
        lossv = 3.0f * ref * ref;
    }

    for (int off = 32; off; off >>= 1) lossv += __shfl_down(lossv, off);
    if ((tid & 63) == 0) wsum[tid >> 6] = lossv;
    __syncthreads();
    if (tid == 0) {
        partial[blockIdx.x] = wsum[0] + wsum[1] + wsum[2] + wsum[3];
        __threadfence();
        unsigned int old = atomicAdd(counter, 1);
        last = (old == (unsigned int)(gridDim.x - 1));
    }
    __syncthreads();
    if (last) {                       // fixed-order sum -> deterministic
        __threadfence();
        float v = partial[tid];
        for (int off = 32; off; off >>= 1) v += __shfl_down(v, off);
        if ((tid & 63) == 0) wsum[tid >> 6] = v;
        __syncthreads();
        if (tid == 0) out[0] = wsum[0] + wsum[1] + wsum[2] + wsum[3];
    }
}

static void make_view(double dist, double elev, double azim, float* M)
{
    double e = elev * M_PI / 180.0, a = azim * M_PI / 180.0;
    float ex = (float)(dist * cos(e) * sin(a));
    float ey = (float)(dist * sin(e));
    float ez = (float)(-dist * cos(e) * cos(a));
    float zx = -ex, zy = -ey, zz = -ez;
    float n = sqrtf(zx * zx + zy * zy + zz * zz);
    zx /= n; zy /= n; zz /= n;
    float xx = zz, xy = 0.0f, xz = -zx;
    n = sqrtf(xx * xx + xy * xy + xz * xz);
    xx /= n; xy /= n; xz /= n;
    float yx = zy * xz - zz * xy;
    float yy = zz * xx - zx * xz;
    float yz = zx * xy - zy * xx;
    n = sqrtf(yx * yx + yy * yy + yz * yz);
    yx /= n; yy /= n; yz /= n;
    M[0] = xx; M[1] = xy; M[2] = xz;
    M[3] = yx; M[4] = yy; M[5] = yz;
    M[6] = zx; M[7] = zy; M[8] = zz;
    M[9] = ex; M[10] = ey; M[11] = ez;
}

extern "C" void kernel_launch(void* const* d_in, const int* in_sizes, int n_in,
                              void* d_out, int out_size, void* d_ws, size_t ws_size,
                              hipStream_t stream)
{
    const float* verts = (const float*)d_in[0];
    const int*   faces = (const int*)d_in[1];
    const float* tex   = (const float*)d_in[2];
    const float* refs  = (const float*)d_in[3];
    float* out = (float*)d_out;

    char* ws = (char*)d_ws;
    float4* fd = (float4*)ws;                             // 4*1024*48B = 192 KB
    ws += (size_t)4 * NF * 3 * sizeof(float4);
    unsigned long long* keys = (unsigned long long*)ws;   // 4*16*16384*8 = 8 MB
    ws += (size_t)4 * NCHUNK * NPIX * sizeof(unsigned long long);
    float* partial = (float*)ws;                          // 256 floats
    ws += 256 * sizeof(float);
    unsigned int* counter = (unsigned int*)ws;            // 4 B

    AllViews vc;
    const double V[4][3] = {{2.83, 45.0, 0.0}, {2.0, 0.0, 90.0},
                            {3.46, 45.0, 45.0}, {3.0, 0.0, 0.0}};
    for (int i = 0; i < 4; ++i) make_view(V[i][0], V[i][1], V[i][2], vc.m[i]);
    float W = (float)tan(M_PI / 6.0);

    precompute<<<16, 256, 0, stream>>>(verts, faces, fd, counter, vc, W);
    raster<<<1024, 256, 0, stream>>>(fd, keys);
    shade_loss<<<256, 256, 0, stream>>>(fd, keys, tex, refs,
                                        partial, counter, out);
}